// Round 1
// baseline (598.727 us; speedup 1.0000x reference)
//
#include <hip/hip_runtime.h>

#define Bn   16
#define Cn   256
#define Hd   128
#define Wd   128
#define HW   16384          // Hd*Wd
#define HW4  4096           // HW/4

#define TWO_PI 6.283185307179586

// workspace layout (floats)
#define OFF_XM   0          // B*HW          = 262144
#define OFF_X00  262144     // B*C           = 4096
#define OFF_CF   266240     // B*C           = 4096
#define OFF_C1   270336     // B*HW          = 262144
#define OFF_S1   532480     // B*HW          = 262144
#define OFF_SF   794624     // B*HW          = 262144
// total 1056768 floats ~= 4.03 MiB

// Kernel 1: channel mean xm[b,h,w] = mean_c x[b,c,h,w]; also extract x00[b,c]=x[b,c,0,0]
__global__ void k1_mean_x00(const float* __restrict__ x,
                            float* __restrict__ xm, float* __restrict__ x00) {
    int tid = blockIdx.x * blockDim.x + threadIdx.x;   // 0 .. B*HW4-1 (65536)
    int b = tid >> 12;                                 // / HW4
    int p = tid & (HW4 - 1);
    const float4* base = (const float4*)x + (size_t)b * Cn * HW4 + p;
    float4 s = {0.f, 0.f, 0.f, 0.f};
    bool isp0 = (p == 0);
    #pragma unroll 4
    for (int c = 0; c < Cn; ++c) {
        float4 v = base[(size_t)c * HW4];
        s.x += v.x; s.y += v.y; s.z += v.z; s.w += v.w;
        if (isp0) x00[b * Cn + c] = v.x;               // x[b,c,0,0]
    }
    const float inv = 1.0f / (float)Cn;
    float4 o = { s.x * inv, s.y * inv, s.z * inv, s.w * inv };
    ((float4*)xm)[(size_t)b * HW4 + p] = o;
}

// Kernel 2: cf[b,c] = sigmoid( sum_k x00[b,k] * W[c,k] + bias[c] )
__global__ void k2_cf(const float* __restrict__ x00, const float* __restrict__ Wm,
                      const float* __restrict__ bias, float* __restrict__ cf) {
    __shared__ float xs[Cn];
    int b = blockIdx.x, c = threadIdx.x;
    xs[c] = x00[b * Cn + c];
    __syncthreads();
    float acc = bias[c];
    const float* wr = Wm + (size_t)c * Cn;
    #pragma unroll 8
    for (int k = 0; k < Cn; ++k) acc = fmaf(xs[k], wr[k], acc);
    cf[b * Cn + c] = 1.0f / (1.0f + expf(-acc));
}

// Kernel 3a: row transform. block=(b,k1), thread=n2.
// C1[b,k1,n2] = sum_n1 cos(2pi k1 n1/128) xm[b,n1,n2]; S1 likewise with sin.
__global__ void k3a_rows(const float* __restrict__ xm,
                         float* __restrict__ C1, float* __restrict__ S1) {
    __shared__ float tc[Hd], ts[Hd];
    int k1 = blockIdx.x & (Hd - 1);
    int b  = blockIdx.x >> 7;
    int n2 = threadIdx.x;
    {
        double ang = (double)n2 * (TWO_PI / (double)Hd);
        tc[n2] = (float)cos(ang);
        ts[n2] = (float)sin(ang);
    }
    __syncthreads();
    float ac = 0.f, as = 0.f;
    const float* xb = xm + (size_t)b * HW + n2;
    #pragma unroll 8
    for (int n1 = 0; n1 < Hd; ++n1) {
        int idx = (k1 * n1) & (Hd - 1);
        float v = xb[(size_t)n1 * Wd];
        ac = fmaf(tc[idx], v, ac);
        as = fmaf(ts[idx], v, as);
    }
    C1[(size_t)b * HW + k1 * Wd + n2] = ac;
    S1[(size_t)b * HW + k1 * Wd + n2] = as;
}

// Kernel 3b: column transform. block=(b,k1), thread=k2.
// sf[b,k1,k2] = sum_n2 cos(2pi k2 n2/128)*C1[b,k1,n2] - sin(...)*S1[b,k1,n2]
__global__ void k3b_cols(const float* __restrict__ C1, const float* __restrict__ S1,
                         float* __restrict__ sf) {
    __shared__ float tc[Wd], ts[Wd], c1s[Wd], s1s[Wd];
    int k1 = blockIdx.x & (Hd - 1);
    int b  = blockIdx.x >> 7;
    int k2 = threadIdx.x;
    {
        double ang = (double)k2 * (TWO_PI / (double)Wd);
        tc[k2] = (float)cos(ang);
        ts[k2] = (float)sin(ang);
        size_t row = (size_t)b * HW + k1 * Wd + k2;
        c1s[k2] = C1[row];
        s1s[k2] = S1[row];
    }
    __syncthreads();
    float acc = 0.f;
    #pragma unroll 8
    for (int n2 = 0; n2 < Wd; ++n2) {
        int idx = (k2 * n2) & (Wd - 1);
        acc = fmaf(tc[idx],  c1s[n2], acc);
        acc = fmaf(-ts[idx], s1s[n2], acc);
    }
    sf[(size_t)b * HW + k1 * Wd + k2] = acc;
}

// Kernel 4: out[b,c,h,w] = x[b,c,h,w] * (cf[b,c] + sf[b,h,w]) — float4 grid-stride
__global__ void k4_out(const float* __restrict__ x, const float* __restrict__ cf,
                       const float* __restrict__ sf, float* __restrict__ out) {
    const size_t n4 = (size_t)Bn * Cn * HW4;            // 16,777,216 float4s
    size_t stride = (size_t)gridDim.x * blockDim.x;
    for (size_t i = (size_t)blockIdx.x * blockDim.x + threadIdx.x; i < n4; i += stride) {
        size_t e = i << 2;                              // element index
        int b   = (int)(e >> 22);                       // / (Cn*HW)
        int c   = (int)((e >> 14) & (Cn - 1));          // / HW % Cn
        int hw4 = (int)(i & (HW4 - 1));
        float cfv = cf[b * Cn + c];
        float4 sv = ((const float4*)sf)[(size_t)b * HW4 + hw4];
        float4 xv = ((const float4*)x)[i];
        float4 o;
        o.x = xv.x * (cfv + sv.x);
        o.y = xv.y * (cfv + sv.y);
        o.z = xv.z * (cfv + sv.z);
        o.w = xv.w * (cfv + sv.w);
        ((float4*)out)[i] = o;
    }
}

extern "C" void kernel_launch(void* const* d_in, const int* in_sizes, int n_in,
                              void* d_out, int out_size, void* d_ws, size_t ws_size,
                              hipStream_t stream) {
    const float* x    = (const float*)d_in[0];
    const float* Wm   = (const float*)d_in[1];
    const float* bias = (const float*)d_in[2];
    float* out = (float*)d_out;
    float* ws  = (float*)d_ws;

    float* xm  = ws + OFF_XM;
    float* x00 = ws + OFF_X00;
    float* cf  = ws + OFF_CF;
    float* C1  = ws + OFF_C1;
    float* S1  = ws + OFF_S1;
    float* sf  = ws + OFF_SF;

    // 1. channel mean + corner extraction: 65536 threads
    k1_mean_x00<<<(Bn * HW4) / 256, 256, 0, stream>>>(x, xm, x00);
    // 2. cf = sigmoid(x00 @ W^T + b): one block per batch
    k2_cf<<<Bn, Cn, 0, stream>>>(x00, Wm, bias, cf);
    // 3. separable real-DFT of xm
    k3a_rows<<<Bn * Hd, Wd, 0, stream>>>(xm, C1, S1);
    k3b_cols<<<Bn * Hd, Wd, 0, stream>>>(C1, S1, sf);
    // 4. fused elementwise output
    k4_out<<<2048, 256, 0, stream>>>(x, cf, sf, out);
}

// Round 2
// 541.793 us; speedup vs baseline: 1.1051x; 1.1051x over previous
//
#include <hip/hip_runtime.h>

#define Bn   16
#define Cn   256
#define Hd   128
#define Wd   128
#define HW   16384          // Hd*Wd
#define HW4  4096           // HW/4

#define SPLIT 8
#define CPS  (Cn / SPLIT)   // 32 channels per split-slice

#define TWO_PI 6.283185307179586

// workspace layout (floats)
#define OFF_XM   0          // B*HW          = 262144
#define OFF_X00  262144     // B*C           = 4096
#define OFF_CF   266240     // B*C           = 4096
#define OFF_C1   270336     // B*HW          = 262144
#define OFF_S1   532480     // B*HW          = 262144
#define OFF_SF   794624     // B*HW          = 262144
// total 1056768 floats ~= 4.03 MiB
// NOTE: 8-way channel partials (8 MiB) live in d_out, which k4 fully overwrites.

// Kernel 1a: partial channel sums. thread (s,b,p) sums channels [s*32, s*32+32)
// at float4-position p of batch b. 524288 threads -> full occupancy.
__global__ void k1a_partial(const float* __restrict__ x, float* __restrict__ part,
                            float* __restrict__ x00) {
    int tid = blockIdx.x * blockDim.x + threadIdx.x;   // 0 .. B*HW4*SPLIT-1
    int p = tid & (HW4 - 1);
    int b = (tid >> 12) & (Bn - 1);
    int s = tid >> 16;
    const float4* base = (const float4*)x + (size_t)b * Cn * HW4 + (size_t)s * CPS * HW4 + p;
    float4 acc = {0.f, 0.f, 0.f, 0.f};
    bool isp0 = (p == 0);
    #pragma unroll
    for (int c = 0; c < CPS; ++c) {
        float4 v = base[(size_t)c * HW4];
        acc.x += v.x; acc.y += v.y; acc.z += v.z; acc.w += v.w;
        if (isp0) x00[b * Cn + s * CPS + c] = v.x;     // x[b,c,0,0]
    }
    ((float4*)part)[((size_t)s * Bn + b) * HW4 + p] = acc;
}

// Kernel 1b: fold the 8 partials -> xm (channel mean). 65536 threads, ~9 MiB traffic.
__global__ void k1b_reduce(const float* __restrict__ part, float* __restrict__ xm) {
    int tid = blockIdx.x * blockDim.x + threadIdx.x;   // 0 .. B*HW4-1
    int b = tid >> 12;
    int p = tid & (HW4 - 1);
    float4 s = {0.f, 0.f, 0.f, 0.f};
    #pragma unroll
    for (int k = 0; k < SPLIT; ++k) {
        float4 v = ((const float4*)part)[((size_t)k * Bn + b) * HW4 + p];
        s.x += v.x; s.y += v.y; s.z += v.z; s.w += v.w;
    }
    const float inv = 1.0f / (float)Cn;
    float4 o = { s.x * inv, s.y * inv, s.z * inv, s.w * inv };
    ((float4*)xm)[(size_t)b * HW4 + p] = o;
}

// Kernel 2: cf[b,c] = sigmoid( sum_k x00[b,k] * W[c,k] + bias[c] )
__global__ void k2_cf(const float* __restrict__ x00, const float* __restrict__ Wm,
                      const float* __restrict__ bias, float* __restrict__ cf) {
    __shared__ float xs[Cn];
    int b = blockIdx.x, c = threadIdx.x;
    xs[c] = x00[b * Cn + c];
    __syncthreads();
    float acc = bias[c];
    const float* wr = Wm + (size_t)c * Cn;
    #pragma unroll 8
    for (int k = 0; k < Cn; ++k) acc = fmaf(xs[k], wr[k], acc);
    cf[b * Cn + c] = 1.0f / (1.0f + expf(-acc));
}

// Kernel 3a: row transform. block=(b,k1), thread=n2.
// C1[b,k1,n2] = sum_n1 cos(2pi k1 n1/128) xm[b,n1,n2]; S1 likewise with sin.
__global__ void k3a_rows(const float* __restrict__ xm,
                         float* __restrict__ C1, float* __restrict__ S1) {
    __shared__ float tc[Hd], ts[Hd];
    int k1 = blockIdx.x & (Hd - 1);
    int b  = blockIdx.x >> 7;
    int n2 = threadIdx.x;
    {
        double ang = (double)n2 * (TWO_PI / (double)Hd);
        tc[n2] = (float)cos(ang);
        ts[n2] = (float)sin(ang);
    }
    __syncthreads();
    float ac = 0.f, as = 0.f;
    const float* xb = xm + (size_t)b * HW + n2;
    #pragma unroll 8
    for (int n1 = 0; n1 < Hd; ++n1) {
        int idx = (k1 * n1) & (Hd - 1);
        float v = xb[(size_t)n1 * Wd];
        ac = fmaf(tc[idx], v, ac);
        as = fmaf(ts[idx], v, as);
    }
    C1[(size_t)b * HW + k1 * Wd + n2] = ac;
    S1[(size_t)b * HW + k1 * Wd + n2] = as;
}

// Kernel 3b: column transform. block=(b,k1), thread=k2.
// sf[b,k1,k2] = sum_n2 cos(2pi k2 n2/128)*C1[b,k1,n2] - sin(...)*S1[b,k1,n2]
__global__ void k3b_cols(const float* __restrict__ C1, const float* __restrict__ S1,
                         float* __restrict__ sf) {
    __shared__ float tc[Wd], ts[Wd], c1s[Wd], s1s[Wd];
    int k1 = blockIdx.x & (Hd - 1);
    int b  = blockIdx.x >> 7;
    int k2 = threadIdx.x;
    {
        double ang = (double)k2 * (TWO_PI / (double)Wd);
        tc[k2] = (float)cos(ang);
        ts[k2] = (float)sin(ang);
        size_t row = (size_t)b * HW + k1 * Wd + k2;
        c1s[k2] = C1[row];
        s1s[k2] = S1[row];
    }
    __syncthreads();
    float acc = 0.f;
    #pragma unroll 8
    for (int n2 = 0; n2 < Wd; ++n2) {
        int idx = (k2 * n2) & (Wd - 1);
        acc = fmaf(tc[idx],  c1s[n2], acc);
        acc = fmaf(-ts[idx], s1s[n2], acc);
    }
    sf[(size_t)b * HW + k1 * Wd + k2] = acc;
}

// Kernel 4: out[b,c,h,w] = x[b,c,h,w] * (cf[b,c] + sf[b,h,w]) — float4 grid-stride
__global__ void k4_out(const float* __restrict__ x, const float* __restrict__ cf,
                       const float* __restrict__ sf, float* __restrict__ out) {
    const size_t n4 = (size_t)Bn * Cn * HW4;            // 16,777,216 float4s
    size_t stride = (size_t)gridDim.x * blockDim.x;
    for (size_t i = (size_t)blockIdx.x * blockDim.x + threadIdx.x; i < n4; i += stride) {
        size_t e = i << 2;                              // element index
        int b   = (int)(e >> 22);                       // / (Cn*HW)
        int c   = (int)((e >> 14) & (Cn - 1));          // / HW % Cn
        int hw4 = (int)(i & (HW4 - 1));
        float cfv = cf[b * Cn + c];
        float4 sv = ((const float4*)sf)[(size_t)b * HW4 + hw4];
        float4 xv = ((const float4*)x)[i];
        float4 o;
        o.x = xv.x * (cfv + sv.x);
        o.y = xv.y * (cfv + sv.y);
        o.z = xv.z * (cfv + sv.z);
        o.w = xv.w * (cfv + sv.w);
        ((float4*)out)[i] = o;
    }
}

extern "C" void kernel_launch(void* const* d_in, const int* in_sizes, int n_in,
                              void* d_out, int out_size, void* d_ws, size_t ws_size,
                              hipStream_t stream) {
    const float* x    = (const float*)d_in[0];
    const float* Wm   = (const float*)d_in[1];
    const float* bias = (const float*)d_in[2];
    float* out = (float*)d_out;
    float* ws  = (float*)d_ws;

    float* xm  = ws + OFF_XM;
    float* x00 = ws + OFF_X00;
    float* cf  = ws + OFF_CF;
    float* C1  = ws + OFF_C1;
    float* S1  = ws + OFF_S1;
    float* sf  = ws + OFF_SF;
    float* part = out;   // d_out doubles as 8 MiB scratch for channel partials

    // 1. channel mean (split 8-way for occupancy) + corner extraction
    k1a_partial<<<(Bn * HW4 * SPLIT) / 256, 256, 0, stream>>>(x, part, x00);
    k1b_reduce<<<(Bn * HW4) / 256, 256, 0, stream>>>(part, xm);
    // 2. cf = sigmoid(x00 @ W^T + b): one block per batch
    k2_cf<<<Bn, Cn, 0, stream>>>(x00, Wm, bias, cf);
    // 3. separable real-DFT of xm
    k3a_rows<<<Bn * Hd, Wd, 0, stream>>>(xm, C1, S1);
    k3b_cols<<<Bn * Hd, Wd, 0, stream>>>(C1, S1, sf);
    // 4. fused elementwise output
    k4_out<<<2048, 256, 0, stream>>>(x, cf, sf, out);
}